// Round 19
// baseline (130.551 us; speedup 1.0000x reference)
//
#include <hip/hip_runtime.h>
#include <hip/hip_bf16.h>
#include <hip/hip_fp16.h>

#define NN   102400
#define NG   64
#define NPG  1600
#define NE   1638400
#define EPG  25600
#define EPC  (EPG / 4)

typedef unsigned int u32;
typedef unsigned short u16;

// ---- ws layout (float offsets) ----
#define OFF_EDAT   0                       // u32[NE]: (snd_local<<16)|bf16(ef), receiver-sorted
#define OFF_FUSED  (NE)                    // uint4[NN]: [A fp8x8 | B fp8x8] per node (hid gather)
#define OFF_PNN    (NE + 4 * NN)           // half[NN*16]: p_nn+ebn -> n1@hWnn^T
#define OFF_SPROJA (NE + 12 * NN)          // half[NN*8]: enc p_es+ebe (f16 compact, enc gather)
#define OFF_DEG    (NE + 16 * NN)          // int[NN]
#define OFF_START  (NE + 17 * NN)          // int[NN]
#define OFF_H4C    (NE + 18 * NN)          // int[4*NN]
#define OFF_GS     (NE + 22 * NN)          // 4864 floats
#define GS_ESUM1 0
#define GS_NSUM1 512
#define GS_ESUM2 1536
#define GS_NSUM2 2048
#define GS_G1    3072

struct H8 { __half2 a, b, c, d; };

__device__ __forceinline__ void unpack8_f4(const float4 v, float* o) {
    const __half2* h = reinterpret_cast<const __half2*>(&v);
    float2 t0 = __half22float2(h[0]), t1 = __half22float2(h[1]);
    float2 t2 = __half22float2(h[2]), t3 = __half22float2(h[3]);
    o[0]=t0.x; o[1]=t0.y; o[2]=t1.x; o[3]=t1.y; o[4]=t2.x; o[5]=t2.y; o[6]=t3.x; o[7]=t3.y;
}
__device__ __forceinline__ void unpack8(const H8 v, float* o) {
    float2 t0 = __half22float2(v.a), t1 = __half22float2(v.b);
    float2 t2 = __half22float2(v.c), t3 = __half22float2(v.d);
    o[0]=t0.x; o[1]=t0.y; o[2]=t1.x; o[3]=t1.y; o[4]=t2.x; o[5]=t2.y; o[6]=t3.x; o[7]=t3.y;
}
__device__ __forceinline__ H8 pack8(const float* v) {
    H8 r;
    r.a = __floats2half2_rn(v[0], v[1]); r.b = __floats2half2_rn(v[2], v[3]);
    r.c = __floats2half2_rn(v[4], v[5]); r.d = __floats2half2_rn(v[6], v[7]);
    return r;
}
__device__ __forceinline__ u16 f2bf(float f) {
    u32 u = __float_as_uint(f);
    return (u16)((u + 0x7fffu + ((u >> 16) & 1u)) >> 16);
}
// f32 -> fp8 e4m3 byte (via f16(x/256) + RNE 10->3 mantissa truncation; clamps to max-mag).
__device__ __forceinline__ u32 pack_fp8x4(const float* v) {
    u32 r = 0;
#pragma unroll
    for (int i = 0; i < 4; ++i) {
        const u32 u = (u32)__half_as_ushort(__float2half(v[i] * (1.f / 256.f)));
        const u32 s = (u & 0x8000u) >> 8;
        u32 mag = u & 0x7fffu;
        mag = (mag + 0x3Fu + ((mag >> 7) & 1u)) >> 7;
        if (mag > 0xffu) mag = 0xffu;   // clamp (values here are < 64, never reached)
        r |= (s | mag) << (8 * i);
    }
    return r;
}
// 4 fp8 bytes -> 4 floats (exact: b -> f16(bits b<<7) * 256, denormals included)
__device__ __forceinline__ void fp8x4_to_f4(u32 t, float* o) {
    u32 lo = ((t & 0x7fu) << 7) | ((t & 0x80u) << 8)
           | ((t & 0x7f00u) << 15) | ((t & 0x8000u) << 16);
    u32 tt = t >> 16;
    u32 hi = ((tt & 0x7fu) << 7) | ((tt & 0x80u) << 8)
           | ((tt & 0x7f00u) << 15) | ((tt & 0x8000u) << 16);
    const float2 a = __half22float2(*reinterpret_cast<const __half2*>(&lo));
    const float2 b = __half22float2(*reinterpret_cast<const __half2*>(&hi));
    o[0] = a.x * 256.f; o[1] = a.y * 256.f; o[2] = b.x * 256.f; o[3] = b.y * 256.f;
}
__device__ __forceinline__ float wsum(float v) {
#pragma unroll
    for (int o = 32; o >= 1; o >>= 1) v += __shfl_xor(v, o);
    return v;
}
__device__ __forceinline__ float sigmoidf_(float x) { return 1.f / (1.f + expf(-x)); }

// H1: per-chunk receiver histogram.
__global__ __launch_bounds__(512) void k_hist4(const int* __restrict__ rcv, int* __restrict__ h4) {
    __shared__ int h[NPG];
    const int g = blockIdx.x >> 2, c = blockIdx.x & 3;
    for (int i = threadIdx.x; i < NPG; i += 512) h[i] = 0;
    __syncthreads();
    const int base = g * EPG + c * EPC;
    for (int t = threadIdx.x; t < EPC; t += 512) atomicAdd(&h[rcv[base + t] - g * NPG], 1);
    __syncthreads();
    int* out = h4 + (size_t)(g * 4 + c) * NPG;
    for (int i = threadIdx.x; i < NPG; i += 512) out[i] = h[i];
}

// H2: per-graph scan (global offsets).
__global__ __launch_bounds__(320) void k_scan(
    int* __restrict__ h4c, int* __restrict__ deg, int* __restrict__ start)
{
    __shared__ int part[320];
    const int g = blockIdx.x, tid = threadIdx.x;
    const int vb = tid * 5;
    int hc[5][4], d[5], pre[5];
    int ts = 0;
#pragma unroll
    for (int i = 0; i < 5; ++i) {
        const int v = vb + i;
#pragma unroll
        for (int c = 0; c < 4; ++c) hc[i][c] = h4c[(size_t)(g * 4 + c) * NPG + v];
        d[i] = hc[i][0] + hc[i][1] + hc[i][2] + hc[i][3];
        pre[i] = ts;
        ts += d[i];
    }
    part[tid] = ts;
    __syncthreads();
    for (int o = 1; o < 320; o <<= 1) {
        const int v = (tid >= o) ? part[tid - o] : 0;
        __syncthreads();
        part[tid] += v;
        __syncthreads();
    }
    const int off = g * EPG + part[tid] - ts;
#pragma unroll
    for (int i = 0; i < 5; ++i) {
        const int v = vb + i;
        const int st = off + pre[i];
        deg[g * NPG + v] = d[i];
        start[g * NPG + v] = st;
        int run = st;
#pragma unroll
        for (int c = 0; c < 4; ++c) {
            h4c[(size_t)(g * 4 + c) * NPG + v] = run;
            run += hc[i][c];
        }
    }
}

// H3: scatter edges into receiver-sorted order via LDS cursors.
__global__ __launch_bounds__(512) void k_scatter4(
    const float* __restrict__ ef, const int* __restrict__ snd, const int* __restrict__ rcv,
    const int* __restrict__ h4c, u32* __restrict__ edat)
{
    __shared__ int cur[NPG];
    const int g = blockIdx.x >> 2, c = blockIdx.x & 3;
    const int* cb = h4c + (size_t)(g * 4 + c) * NPG;
    for (int i = threadIdx.x; i < NPG; i += 512) cur[i] = cb[i];
    __syncthreads();
    const int base = g * EPG + c * EPC;
    for (int t = threadIdx.x; t < EPC; t += 512) {
        const int e = base + t;
        const int r = rcv[e] - g * NPG;
        const int p = atomicAdd(&cur[r], 1);
        const u32 s = (u32)(snd[e] - g * NPG);
        edat[p] = (s << 16) | (u32)f2bf(ef[e]);
    }
}

// K1: per-node encoder pre-projections; writes f16 compact A + fp8 A-half of fused; zeroes gs.
__global__ __launch_bounds__(256) void k_node_pre(
    const float* __restrict__ nf,
    const float* __restrict__ Wes, const float* __restrict__ Wnn,
    const float* __restrict__ ebe, const float* __restrict__ ebn,
    __half* __restrict__ pnn, __half* __restrict__ sprojAc,
    uint2* __restrict__ fused2, float* __restrict__ gs)
{
    __shared__ float wE[480], wN[960];
    for (int i = threadIdx.x; i < 480; i += 256) wE[i] = Wes[i];
    for (int i = threadIdx.x; i < 960; i += 256) wN[i] = Wnn[i];
    if (blockIdx.x == 0) {
        for (int i = threadIdx.x; i < 3072; i += 256) gs[i] = 0.f;
    }
    __syncthreads();
    const int v = blockIdx.x * 256 + threadIdx.x;
    const float4* row = reinterpret_cast<const float4*>(nf + (size_t)v * 60);
    float x[60];
#pragma unroll
    for (int i = 0; i < 15; ++i) {
        const float4 a = row[i];
        x[4 * i] = a.x; x[4 * i + 1] = a.y; x[4 * i + 2] = a.z; x[4 * i + 3] = a.w;
    }
    float pes[8], pn[16];
#pragma unroll
    for (int j = 0; j < 8; ++j) pes[j] = ebe[j];
#pragma unroll
    for (int j = 0; j < 16; ++j) pn[j] = ebn[j];
#pragma unroll
    for (int k = 0; k < 60; ++k) {
        const float xv = x[k];
#pragma unroll
        for (int j = 0; j < 8; ++j)  pes[j] = fmaf(xv, wE[j * 60 + k], pes[j]);
#pragma unroll
        for (int j = 0; j < 16; ++j) pn[j]  = fmaf(xv, wN[j * 60 + k], pn[j]);
    }
    reinterpret_cast<H8*>(sprojAc)[v] = pack8(pes);
    fused2[(size_t)v * 2] = make_uint2(pack_fp8x4(pes), pack_fp8x4(pes + 4));
    H8* pp = reinterpret_cast<H8*>(pnn) + (size_t)v * 2;
    pp[0] = pack8(pn); pp[1] = pack8(pn + 8);
}

// K2: encoder edge gather (uint4 edat; f16 compact A-table) + node layer; writes fp8 B-half.
__global__ __launch_bounds__(256) void k_enc4(
    const int* __restrict__ deg, const int* __restrict__ start, const u32* __restrict__ edat,
    const __half* __restrict__ sprojAc,
    uint2* __restrict__ fused2, __half* __restrict__ pnn,
    const float* __restrict__ eWee, const float* __restrict__ eWni,
    const float* __restrict__ hWes, const float* __restrict__ hWnn,
    float* __restrict__ esum, float* __restrict__ nsum)
{
    __shared__ float wNI[128], wES[128], wNN2[256];
    const int tid = threadIdx.x, lane = tid & 63;
    for (int i = tid; i < 128; i += 256) { wNI[i] = eWni[i]; wES[i] = hWes[i]; }
    wNN2[tid] = hWnn[tid];
    __syncthreads();
    const int v = blockIdx.x * 256 + tid;
    const int g = v / NPG;   // waves never span graphs (1600 % 64 == 0)
    float wee[8];
#pragma unroll
    for (int j = 0; j < 8; ++j) wee[j] = eWee[j];
    const int dg = deg[v];
    const int st = start[v];
    const int aend = st + dg;
    float m[8];
#pragma unroll
    for (int j = 0; j < 8; ++j) m[j] = 0.f;
    const float4* hbA = reinterpret_cast<const float4*>(sprojAc) + (size_t)g * NPG;

    for (int i = st & ~3; i < aend; i += 4) {
        const uint4 w4 = *reinterpret_cast<const uint4*>(edat + i);
        const u32 w[4] = {w4.x, w4.y, w4.z, w4.w};
        float4 A[4];
#pragma unroll
        for (int j = 0; j < 4; ++j) A[j] = hbA[w[j] >> 16];
#pragma unroll
        for (int j = 0; j < 4; ++j) {
            const int idx = i + j;
            const float val = (idx >= st && idx < aend) ? 1.f : 0.f;
            const float f = __uint_as_float((w[j] & 0xffffu) << 16);
            float pv[8]; unpack8_f4(A[j], pv);
#pragma unroll
            for (int k = 0; k < 8; ++k) m[k] += val * fmaxf(0.f, fmaf(f, wee[k], pv[k]));
        }
    }
#pragma unroll
    for (int j = 0; j < 8; ++j) {
        const float s = wsum(m[j]);
        if (lane == 0) atomicAdd(&esum[g * 8 + j], s);
    }
    const float ic = 1.f / fmaxf((float)dg, 1.f);
    float mk[8];
#pragma unroll
    for (int k = 0; k < 8; ++k) mk[k] = m[k] * ic;
    H8* pp = reinterpret_cast<H8*>(pnn) + (size_t)v * 2;
    float pn[16]; unpack8(pp[0], pn); unpack8(pp[1], pn + 8);
    float n1[16];
#pragma unroll
    for (int j = 0; j < 16; ++j) {
        float x = pn[j];
#pragma unroll
        for (int k = 0; k < 8; ++k) x = fmaf(mk[k], wNI[j * 8 + k], x);
        n1[j] = fmaxf(0.f, x);
    }
    float pe[8];
#pragma unroll
    for (int o = 0; o < 8; ++o) {
        float x = 0.f;
#pragma unroll
        for (int j = 0; j < 16; ++j) x = fmaf(n1[j], wES[o * 16 + j], x);
        pe[o] = x;
    }
    fused2[(size_t)v * 2 + 1] = make_uint2(pack_fp8x4(pe), pack_fp8x4(pe + 4));
    float pw[16];
#pragma unroll
    for (int o = 0; o < 16; ++o) {
        float x = 0.f;
#pragma unroll
        for (int j = 0; j < 16; ++j) x = fmaf(n1[j], wNN2[o * 16 + j], x);
        pw[o] = x;
    }
    pp[0] = pack8(pw); pp[1] = pack8(pw + 8);
#pragma unroll
    for (int j = 0; j < 16; ++j) {
        const float s = wsum(n1[j]);
        if (lane == 0) atomicAdd(&nsum[g * 16 + j], s);
    }
}

// K3: hidden edge — ONE fused 16B gather (A+B fp8) per edge + node layer + readout.
// Encoder-global layer recomputed per block (replaces k_glob_enc dispatch; bit-identical per graph).
__global__ __launch_bounds__(256) void k_hid7(
    const int* __restrict__ deg, const int* __restrict__ start, const u32* __restrict__ edat,
    const uint4* __restrict__ fused4, const __half* __restrict__ pnn,
    const float* __restrict__ eWee,
    const float* __restrict__ esum1, const float* __restrict__ nsum1,
    const float* __restrict__ eWge, const float* __restrict__ eWgn, const float* __restrict__ ebg,
    const float* __restrict__ hWeg, const float* __restrict__ hWng, float* __restrict__ g1,
    const float* __restrict__ hWee, const float* __restrict__ hbe,
    const float* __restrict__ hWni, const float* __restrict__ hbn,
    const float* __restrict__ roWn, const float* __restrict__ robn,
    float* __restrict__ esum, float* __restrict__ nsum, float* __restrict__ outn)
{
    __shared__ float w2[64], wNI[128], rW[16];
    const int tid = threadIdx.x, lane = tid & 63;
    for (int i = tid; i < 128; i += 256) wNI[i] = hWni[i];
    if (tid < 64) w2[tid] = hWee[tid];
    if (tid < 16) rW[tid] = roWn[tid];
    __syncthreads();
    const int v = blockIdx.x * 256 + tid;
    const int g = v / NPG;
    float wee[8];
#pragma unroll
    for (int j = 0; j < 8; ++j) wee[j] = eWee[j];
    // ---- per-block encoder-global recompute (bit-identical across blocks of graph g) ----
    float gv[4];
#pragma unroll
    for (int o = 0; o < 4; ++o) {
        float x = ebg[o];
#pragma unroll
        for (int k = 0; k < 8; ++k)  x = fmaf(esum1[g * 8 + k] * (1.f / EPG), eWge[o * 8 + k], x);
#pragma unroll
        for (int k = 0; k < 16; ++k) x = fmaf(nsum1[g * 16 + k] * (1.f / NPG), eWgn[o * 16 + k], x);
        gv[o] = fmaxf(0.f, x);
    }
    if (tid < 4) g1[g * 4 + tid] = gv[tid];
    float add2[8];
#pragma unroll
    for (int j = 0; j < 8; ++j) {
        float x = 0.f;
#pragma unroll
        for (int o = 0; o < 4; ++o) x = fmaf(gv[o], hWeg[j * 4 + o], x);
        add2[j] = x + hbe[j];
    }
    float gpnl[16];
#pragma unroll
    for (int j = 0; j < 16; ++j) {
        float x = 0.f;
#pragma unroll
        for (int o = 0; o < 4; ++o) x = fmaf(gv[o], hWng[j * 4 + o], x);
        gpnl[j] = x;
    }
    // ---- edge loop: one fused 16B gather per edge ----
    const int dg = deg[v];
    const int st = start[v];
    const int aend = st + dg;
    float m2[8];
#pragma unroll
    for (int j = 0; j < 8; ++j) m2[j] = 0.f;
    const uint4* hbF = fused4 + (size_t)g * NPG;

    for (int i = st & ~3; i < aend; i += 4) {
        const uint4 w4 = *reinterpret_cast<const uint4*>(edat + i);
        const u32 w[4] = {w4.x, w4.y, w4.z, w4.w};
        uint4 F[4];
#pragma unroll
        for (int j = 0; j < 4; ++j) F[j] = hbF[w[j] >> 16];
#pragma unroll
        for (int j = 0; j < 4; ++j) {
            const int idx = i + j;
            const float val = (idx >= st && idx < aend) ? 1.f : 0.f;
            const float f = __uint_as_float((w[j] & 0xffffu) << 16);
            float pv[8], qv[8];
            fp8x4_to_f4(F[j].x, pv); fp8x4_to_f4(F[j].y, pv + 4);
            fp8x4_to_f4(F[j].z, qv); fp8x4_to_f4(F[j].w, qv + 4);
            float e1[8];
#pragma unroll
            for (int k = 0; k < 8; ++k) e1[k] = fmaxf(0.f, fmaf(f, wee[k], pv[k]));
#pragma unroll
            for (int k = 0; k < 8; ++k) {
                float x = qv[k] + add2[k];
#pragma unroll
                for (int kk = 0; kk < 8; ++kk) x = fmaf(e1[kk], w2[k * 8 + kk], x);
                m2[k] += val * fmaxf(0.f, x);
            }
        }
    }
#pragma unroll
    for (int j = 0; j < 8; ++j) {
        const float s = wsum(m2[j]);
        if (lane == 0) atomicAdd(&esum[g * 8 + j], s);
    }
    const float ic = 1.f / fmaxf((float)dg, 1.f);
    float mk[8];
#pragma unroll
    for (int k = 0; k < 8; ++k) mk[k] = m2[k] * ic;
    const H8* pp = reinterpret_cast<const H8*>(pnn) + (size_t)v * 2;
    float pn[16]; unpack8(pp[0], pn); unpack8(pp[1], pn + 8);
    float z = robn[0];
    float n2[16];
#pragma unroll
    for (int j = 0; j < 16; ++j) {
        float x = pn[j] + gpnl[j] + hbn[j];
#pragma unroll
        for (int k = 0; k < 8; ++k) x = fmaf(mk[k], wNI[j * 8 + k], x);
        n2[j] = fmaxf(0.f, x);
        z = fmaf(n2[j], rW[j], z);
    }
    outn[v] = sigmoidf_(z);
#pragma unroll
    for (int j = 0; j < 16; ++j) {
        const float s = wsum(n2[j]);
        if (lane == 0) atomicAdd(&nsum[g * 16 + j], s);
    }
}

// K4: hidden global layer + global readout.
__global__ void k_glob_hid(
    const float* __restrict__ esum2, const float* __restrict__ nsum2, const float* __restrict__ g1,
    const float* __restrict__ hWge, const float* __restrict__ hWgn,
    const float* __restrict__ hWgg, const float* __restrict__ hbg,
    const float* __restrict__ roWg, const float* __restrict__ robg,
    float* __restrict__ outg)
{
    const int g = threadIdx.x;
    if (g >= NG) return;
    float gv[4];
#pragma unroll
    for (int o = 0; o < 4; ++o) {
        float x = hbg[o];
#pragma unroll
        for (int k = 0; k < 8; ++k)  x = fmaf(esum2[g * 8 + k] * (1.f / EPG), hWge[o * 8 + k], x);
#pragma unroll
        for (int k = 0; k < 16; ++k) x = fmaf(nsum2[g * 16 + k] * (1.f / NPG), hWgn[o * 16 + k], x);
#pragma unroll
        for (int k = 0; k < 4; ++k)  x = fmaf(g1[g * 4 + k], hWgg[o * 4 + k], x);
        gv[o] = fmaxf(0.f, x);
    }
    float z = robg[0];
#pragma unroll
    for (int o = 0; o < 4; ++o) z = fmaf(gv[o], roWg[o], z);
    outg[g] = sigmoidf_(z);
}

extern "C" void kernel_launch(void* const* d_in, const int* in_sizes, int n_in,
                              void* d_out, int out_size, void* d_ws, size_t ws_size,
                              hipStream_t stream)
{
    const float* nf   = (const float*)d_in[0];
    const float* ef   = (const float*)d_in[1];
    const int*   snd  = (const int*)d_in[2];
    const int*   rcv  = (const int*)d_in[3];
    const float* eWee = (const float*)d_in[6];
    const float* eWes = (const float*)d_in[7];
    const float* ebe  = (const float*)d_in[8];
    const float* eWnn = (const float*)d_in[9];
    const float* eWni = (const float*)d_in[10];
    const float* ebn  = (const float*)d_in[11];
    const float* eWge = (const float*)d_in[12];
    const float* eWgn = (const float*)d_in[13];
    const float* ebg  = (const float*)d_in[14];
    const float* hWee = (const float*)d_in[15];
    const float* hWes = (const float*)d_in[16];
    const float* hWeg = (const float*)d_in[17];
    const float* hbe  = (const float*)d_in[18];
    const float* hWnn = (const float*)d_in[19];
    const float* hWni = (const float*)d_in[20];
    const float* hWng = (const float*)d_in[21];
    const float* hbn  = (const float*)d_in[22];
    const float* hWge = (const float*)d_in[23];
    const float* hWgn = (const float*)d_in[24];
    const float* hWgg = (const float*)d_in[25];
    const float* hbg  = (const float*)d_in[26];
    const float* roWn = (const float*)d_in[27];
    const float* robn = (const float*)d_in[28];
    const float* roWg = (const float*)d_in[29];
    const float* robg = (const float*)d_in[30];

    float*  ws     = (float*)d_ws;
    u32*    edat   = (u32*)(ws + OFF_EDAT);
    uint2*  fused2 = (uint2*)(ws + OFF_FUSED);
    uint4*  fused4 = (uint4*)(ws + OFF_FUSED);
    __half* pnn    = (__half*)(ws + OFF_PNN);
    __half* sprojA = (__half*)(ws + OFF_SPROJA);
    int*    deg    = (int*)(ws + OFF_DEG);
    int*    start  = (int*)(ws + OFF_START);
    int*    h4c    = (int*)(ws + OFF_H4C);
    float*  gs     = ws + OFF_GS;
    float* esum1 = gs + GS_ESUM1;
    float* nsum1 = gs + GS_NSUM1;
    float* esum2 = gs + GS_ESUM2;
    float* nsum2 = gs + GS_NSUM2;
    float* g1    = gs + GS_G1;
    float* out   = (float*)d_out;

    k_hist4<<<NG * 4, 512, 0, stream>>>(rcv, h4c);
    k_scan<<<NG, 320, 0, stream>>>(h4c, deg, start);
    k_scatter4<<<NG * 4, 512, 0, stream>>>(ef, snd, rcv, h4c, edat);
    k_node_pre<<<NN / 256, 256, 0, stream>>>(nf, eWes, eWnn, ebe, ebn, pnn, sprojA, fused2, gs);
    k_enc4<<<NN / 256, 256, 0, stream>>>(deg, start, edat, sprojA, fused2, pnn,
                                         eWee, eWni, hWes, hWnn, esum1, nsum1);
    k_hid7<<<NN / 256, 256, 0, stream>>>(deg, start, edat, fused4, pnn, eWee,
                                         esum1, nsum1, eWge, eWgn, ebg, hWeg, hWng, g1,
                                         hWee, hbe, hWni, hbn, roWn, robn,
                                         esum2, nsum2, out);
    k_glob_hid<<<1, 64, 0, stream>>>(esum2, nsum2, g1, hWge, hWgn, hWgg, hbg, roWg, robg, out + NN);
}

// Round 20
// 126.920 us; speedup vs baseline: 1.0286x; 1.0286x over previous
//
#include <hip/hip_runtime.h>
#include <hip/hip_bf16.h>
#include <hip/hip_fp16.h>

#define NN   102400
#define NG   64
#define NPG  1600
#define NE   1638400
#define EPG  25600
#define EPC  (EPG / 4)

typedef unsigned int u32;
typedef unsigned short u16;

// ---- ws layout (float offsets), ~17.2 MB (ws ~268 MB) ----
#define OFF_EDAT   0                       // u32[NE]: (snd_local<<16)|bf16(ef), receiver-sorted
#define OFF_SPROJ  (NE)                    // half[NN*16]: interleaved [A=p_es+ebe | B=pes2] per node
#define OFF_PNN    (NE + 8 * NN)           // half[NN*16]: p_nn+ebn -> n1@hWnn^T
#define OFF_SPROJA (NE + 16 * NN)          // half[NN*8]: compact A copy (L1-friendly gathers for enc)
#define OFF_DEG    (NE + 20 * NN)          // int[NN]
#define OFF_START  (NE + 21 * NN)          // int[NN]
#define OFF_H4C    (NE + 22 * NN)          // int[4*NN]
#define OFF_GS     (NE + 26 * NN)          // 4864 floats
#define GS_ESUM1 0
#define GS_NSUM1 512
#define GS_ESUM2 1536
#define GS_NSUM2 2048
#define GS_G1    3072
#define GS_GPE   3328
#define GS_GPN   3840

struct H8 { __half2 a, b, c, d; };

__device__ __forceinline__ void unpack8_f4(const float4 v, float* o) {
    const __half2* h = reinterpret_cast<const __half2*>(&v);
    float2 t0 = __half22float2(h[0]), t1 = __half22float2(h[1]);
    float2 t2 = __half22float2(h[2]), t3 = __half22float2(h[3]);
    o[0]=t0.x; o[1]=t0.y; o[2]=t1.x; o[3]=t1.y; o[4]=t2.x; o[5]=t2.y; o[6]=t3.x; o[7]=t3.y;
}
__device__ __forceinline__ void unpack8(const H8 v, float* o) {
    float2 t0 = __half22float2(v.a), t1 = __half22float2(v.b);
    float2 t2 = __half22float2(v.c), t3 = __half22float2(v.d);
    o[0]=t0.x; o[1]=t0.y; o[2]=t1.x; o[3]=t1.y; o[4]=t2.x; o[5]=t2.y; o[6]=t3.x; o[7]=t3.y;
}
__device__ __forceinline__ H8 pack8(const float* v) {
    H8 r;
    r.a = __floats2half2_rn(v[0], v[1]); r.b = __floats2half2_rn(v[2], v[3]);
    r.c = __floats2half2_rn(v[4], v[5]); r.d = __floats2half2_rn(v[6], v[7]);
    return r;
}
__device__ __forceinline__ u16 f2bf(float f) {
    u32 u = __float_as_uint(f);
    return (u16)((u + 0x7fffu + ((u >> 16) & 1u)) >> 16);
}
__device__ __forceinline__ float wsum(float v) {
#pragma unroll
    for (int o = 32; o >= 1; o >>= 1) v += __shfl_xor(v, o);
    return v;
}
__device__ __forceinline__ float sigmoidf_(float x) { return 1.f / (1.f + expf(-x)); }

// H1: per-chunk receiver histogram.
__global__ __launch_bounds__(512) void k_hist4(const int* __restrict__ rcv, int* __restrict__ h4) {
    __shared__ int h[NPG];
    const int g = blockIdx.x >> 2, c = blockIdx.x & 3;
    for (int i = threadIdx.x; i < NPG; i += 512) h[i] = 0;
    __syncthreads();
    const int base = g * EPG + c * EPC;
    for (int t = threadIdx.x; t < EPC; t += 512) atomicAdd(&h[rcv[base + t] - g * NPG], 1);
    __syncthreads();
    int* out = h4 + (size_t)(g * 4 + c) * NPG;
    for (int i = threadIdx.x; i < NPG; i += 512) out[i] = h[i];
}

// H2: per-graph scan (global offsets).
__global__ __launch_bounds__(320) void k_scan(
    int* __restrict__ h4c, int* __restrict__ deg, int* __restrict__ start)
{
    __shared__ int part[320];
    const int g = blockIdx.x, tid = threadIdx.x;
    const int vb = tid * 5;
    int hc[5][4], d[5], pre[5];
    int ts = 0;
#pragma unroll
    for (int i = 0; i < 5; ++i) {
        const int v = vb + i;
#pragma unroll
        for (int c = 0; c < 4; ++c) hc[i][c] = h4c[(size_t)(g * 4 + c) * NPG + v];
        d[i] = hc[i][0] + hc[i][1] + hc[i][2] + hc[i][3];
        pre[i] = ts;
        ts += d[i];
    }
    part[tid] = ts;
    __syncthreads();
    for (int o = 1; o < 320; o <<= 1) {
        const int v = (tid >= o) ? part[tid - o] : 0;
        __syncthreads();
        part[tid] += v;
        __syncthreads();
    }
    const int off = g * EPG + part[tid] - ts;
#pragma unroll
    for (int i = 0; i < 5; ++i) {
        const int v = vb + i;
        const int st = off + pre[i];
        deg[g * NPG + v] = d[i];
        start[g * NPG + v] = st;
        int run = st;
#pragma unroll
        for (int c = 0; c < 4; ++c) {
            h4c[(size_t)(g * 4 + c) * NPG + v] = run;
            run += hc[i][c];
        }
    }
}

// H3: scatter edges into receiver-sorted order via LDS cursors.
__global__ __launch_bounds__(512) void k_scatter4(
    const float* __restrict__ ef, const int* __restrict__ snd, const int* __restrict__ rcv,
    const int* __restrict__ h4c, u32* __restrict__ edat)
{
    __shared__ int cur[NPG];
    const int g = blockIdx.x >> 2, c = blockIdx.x & 3;
    const int* cb = h4c + (size_t)(g * 4 + c) * NPG;
    for (int i = threadIdx.x; i < NPG; i += 512) cur[i] = cb[i];
    __syncthreads();
    const int base = g * EPG + c * EPC;
    for (int t = threadIdx.x; t < EPC; t += 512) {
        const int e = base + t;
        const int r = rcv[e] - g * NPG;
        const int p = atomicAdd(&cur[r], 1);
        const u32 s = (u32)(snd[e] - g * NPG);
        edat[p] = (s << 16) | (u32)f2bf(ef[e]);
    }
}

// K1: per-node encoder pre-projections; biases folded; writes interleaved A + compact A; zeroes gs.
__global__ __launch_bounds__(256) void k_node_pre(
    const float* __restrict__ nf,
    const float* __restrict__ Wes, const float* __restrict__ Wnn,
    const float* __restrict__ ebe, const float* __restrict__ ebn,
    __half* __restrict__ sproj, __half* __restrict__ pnn,
    __half* __restrict__ sprojAc, float* __restrict__ gs)
{
    __shared__ float wE[480], wN[960];
    for (int i = threadIdx.x; i < 480; i += 256) wE[i] = Wes[i];
    for (int i = threadIdx.x; i < 960; i += 256) wN[i] = Wnn[i];
    if (blockIdx.x == 0) {
        for (int i = threadIdx.x; i < 3072; i += 256) gs[i] = 0.f;
    }
    __syncthreads();
    const int v = blockIdx.x * 256 + threadIdx.x;
    const float4* row = reinterpret_cast<const float4*>(nf + (size_t)v * 60);
    float x[60];
#pragma unroll
    for (int i = 0; i < 15; ++i) {
        const float4 a = row[i];
        x[4 * i] = a.x; x[4 * i + 1] = a.y; x[4 * i + 2] = a.z; x[4 * i + 3] = a.w;
    }
    float pes[8], pn[16];
#pragma unroll
    for (int j = 0; j < 8; ++j) pes[j] = ebe[j];
#pragma unroll
    for (int j = 0; j < 16; ++j) pn[j] = ebn[j];
#pragma unroll
    for (int k = 0; k < 60; ++k) {
        const float xv = x[k];
#pragma unroll
        for (int j = 0; j < 8; ++j)  pes[j] = fmaf(xv, wE[j * 60 + k], pes[j]);
#pragma unroll
        for (int j = 0; j < 16; ++j) pn[j]  = fmaf(xv, wN[j * 60 + k], pn[j]);
    }
    const H8 pa = pack8(pes);
    reinterpret_cast<H8*>(sproj)[(size_t)v * 2] = pa;
    reinterpret_cast<H8*>(sprojAc)[v] = pa;
    H8* pp = reinterpret_cast<H8*>(pnn) + (size_t)v * 2;
    pp[0] = pack8(pn); pp[1] = pack8(pn + 8);
}

// K2: encoder edge gather (uint4 edat; compact A-table) + node layer.
__global__ __launch_bounds__(256) void k_enc4(
    const int* __restrict__ deg, const int* __restrict__ start, const u32* __restrict__ edat,
    const __half* __restrict__ sprojAc,
    __half* __restrict__ sproj, __half* __restrict__ pnn,
    const float* __restrict__ eWee, const float* __restrict__ eWni,
    const float* __restrict__ hWes, const float* __restrict__ hWnn,
    float* __restrict__ esum, float* __restrict__ nsum)
{
    __shared__ float wNI[128], wES[128], wNN2[256];
    const int tid = threadIdx.x, lane = tid & 63;
    for (int i = tid; i < 128; i += 256) { wNI[i] = eWni[i]; wES[i] = hWes[i]; }
    wNN2[tid] = hWnn[tid];
    __syncthreads();
    const int v = blockIdx.x * 256 + tid;
    const int g = v / NPG;   // waves never span graphs (1600 % 64 == 0)
    float wee[8];
#pragma unroll
    for (int j = 0; j < 8; ++j) wee[j] = eWee[j];
    const int dg = deg[v];
    const int st = start[v];
    const int aend = st + dg;
    float m[8];
#pragma unroll
    for (int j = 0; j < 8; ++j) m[j] = 0.f;
    const float4* hbA = reinterpret_cast<const float4*>(sprojAc) + (size_t)g * NPG;

    for (int i = st & ~3; i < aend; i += 4) {
        const uint4 w4 = *reinterpret_cast<const uint4*>(edat + i);
        const u32 w[4] = {w4.x, w4.y, w4.z, w4.w};
        float4 A[4];
#pragma unroll
        for (int j = 0; j < 4; ++j) A[j] = hbA[w[j] >> 16];
#pragma unroll
        for (int j = 0; j < 4; ++j) {
            const int idx = i + j;
            const float val = (idx >= st && idx < aend) ? 1.f : 0.f;
            const float f = __uint_as_float((w[j] & 0xffffu) << 16);
            float pv[8]; unpack8_f4(A[j], pv);
#pragma unroll
            for (int k = 0; k < 8; ++k) m[k] += val * fmaxf(0.f, fmaf(f, wee[k], pv[k]));
        }
    }
#pragma unroll
    for (int j = 0; j < 8; ++j) {
        const float s = wsum(m[j]);
        if (lane == 0) atomicAdd(&esum[g * 8 + j], s);
    }
    const float ic = 1.f / fmaxf((float)dg, 1.f);
    float mk[8];
#pragma unroll
    for (int k = 0; k < 8; ++k) mk[k] = m[k] * ic;
    H8* pp = reinterpret_cast<H8*>(pnn) + (size_t)v * 2;
    float pn[16]; unpack8(pp[0], pn); unpack8(pp[1], pn + 8);
    float n1[16];
#pragma unroll
    for (int j = 0; j < 16; ++j) {
        float x = pn[j];
#pragma unroll
        for (int k = 0; k < 8; ++k) x = fmaf(mk[k], wNI[j * 8 + k], x);
        n1[j] = fmaxf(0.f, x);
    }
    float pe[8];
#pragma unroll
    for (int o = 0; o < 8; ++o) {
        float x = 0.f;
#pragma unroll
        for (int j = 0; j < 16; ++j) x = fmaf(n1[j], wES[o * 16 + j], x);
        pe[o] = x;
    }
    reinterpret_cast<H8*>(sproj)[(size_t)v * 2 + 1] = pack8(pe);
    float pw[16];
#pragma unroll
    for (int o = 0; o < 16; ++o) {
        float x = 0.f;
#pragma unroll
        for (int j = 0; j < 16; ++j) x = fmaf(n1[j], wNN2[o * 16 + j], x);
        pw[o] = x;
    }
    pp[0] = pack8(pw); pp[1] = pack8(pw + 8);
#pragma unroll
    for (int j = 0; j < 16; ++j) {
        const float s = wsum(n1[j]);
        if (lane == 0) atomicAdd(&nsum[g * 16 + j], s);
    }
}

// K3: encoder global layer + g1 projections.
__global__ void k_glob_enc(
    const float* __restrict__ esum1, const float* __restrict__ nsum1,
    const float* __restrict__ Wge, const float* __restrict__ Wgn, const float* __restrict__ bg,
    const float* __restrict__ hWeg, const float* __restrict__ hWng,
    float* __restrict__ g1, float* __restrict__ gpe, float* __restrict__ gpn)
{
    const int g = threadIdx.x;
    if (g >= NG) return;
    float gv[4];
#pragma unroll
    for (int o = 0; o < 4; ++o) {
        float x = bg[o];
#pragma unroll
        for (int k = 0; k < 8; ++k)  x = fmaf(esum1[g * 8 + k] * (1.f / EPG), Wge[o * 8 + k], x);
#pragma unroll
        for (int k = 0; k < 16; ++k) x = fmaf(nsum1[g * 16 + k] * (1.f / NPG), Wgn[o * 16 + k], x);
        gv[o] = fmaxf(0.f, x);
        g1[g * 4 + o] = gv[o];
    }
#pragma unroll
    for (int j = 0; j < 8; ++j) {
        float x = 0.f;
#pragma unroll
        for (int o = 0; o < 4; ++o) x = fmaf(gv[o], hWeg[j * 4 + o], x);
        gpe[g * 8 + j] = x;
    }
#pragma unroll
    for (int j = 0; j < 16; ++j) {
        float x = 0.f;
#pragma unroll
        for (int o = 0; o < 4; ++o) x = fmaf(gv[o], hWng[j * 4 + o], x);
        gpn[g * 16 + j] = x;
    }
}

// K4: hidden edge gather (uint4 edat; interleaved A+B same 64B line) + node layer + readout.
__global__ __launch_bounds__(256) void k_hid4(
    const int* __restrict__ deg, const int* __restrict__ start, const u32* __restrict__ edat,
    const __half* __restrict__ sproj, const __half* __restrict__ pnn,
    const float* __restrict__ eWee,
    const float* __restrict__ hWee, const float* __restrict__ hbe, const float* __restrict__ gpe,
    const float* __restrict__ hWni, const float* __restrict__ hbn, const float* __restrict__ gpn,
    const float* __restrict__ roWn, const float* __restrict__ robn,
    float* __restrict__ esum, float* __restrict__ nsum, float* __restrict__ outn)
{
    __shared__ float w2[64], wNI[128], rW[16];
    const int tid = threadIdx.x, lane = tid & 63;
    for (int i = tid; i < 128; i += 256) wNI[i] = hWni[i];
    if (tid < 64) w2[tid] = hWee[tid];
    if (tid < 16) rW[tid] = roWn[tid];
    __syncthreads();
    const int v = blockIdx.x * 256 + tid;
    const int g = v / NPG;
    float wee[8], add2[8];
#pragma unroll
    for (int j = 0; j < 8; ++j) { wee[j] = eWee[j]; add2[j] = gpe[g * 8 + j] + hbe[j]; }
    const int dg = deg[v];
    const int st = start[v];
    const int aend = st + dg;
    float m2[8];
#pragma unroll
    for (int j = 0; j < 8; ++j) m2[j] = 0.f;
    const float4* hb4 = reinterpret_cast<const float4*>(sproj) + (size_t)g * NPG * 2;

    for (int i = st & ~3; i < aend; i += 4) {
        const uint4 w4 = *reinterpret_cast<const uint4*>(edat + i);
        const u32 w[4] = {w4.x, w4.y, w4.z, w4.w};
        float4 A[4], B[4];
#pragma unroll
        for (int j = 0; j < 4; ++j) {
            const size_t so = (size_t)(w[j] >> 16) * 2;
            A[j] = hb4[so]; B[j] = hb4[so + 1];
        }
#pragma unroll
        for (int j = 0; j < 4; ++j) {
            const int idx = i + j;
            const float val = (idx >= st && idx < aend) ? 1.f : 0.f;
            const float f = __uint_as_float((w[j] & 0xffffu) << 16);
            float pv[8], qv[8];
            unpack8_f4(A[j], pv); unpack8_f4(B[j], qv);
            float e1[8];
#pragma unroll
            for (int k = 0; k < 8; ++k) e1[k] = fmaxf(0.f, fmaf(f, wee[k], pv[k]));
#pragma unroll
            for (int k = 0; k < 8; ++k) {
                float x = qv[k] + add2[k];
#pragma unroll
                for (int kk = 0; kk < 8; ++kk) x = fmaf(e1[kk], w2[k * 8 + kk], x);
                m2[k] += val * fmaxf(0.f, x);
            }
        }
    }
#pragma unroll
    for (int j = 0; j < 8; ++j) {
        const float s = wsum(m2[j]);
        if (lane == 0) atomicAdd(&esum[g * 8 + j], s);
    }
    const float ic = 1.f / fmaxf((float)dg, 1.f);
    float mk[8];
#pragma unroll
    for (int k = 0; k < 8; ++k) mk[k] = m2[k] * ic;
    const H8* pp = reinterpret_cast<const H8*>(pnn) + (size_t)v * 2;
    float pn[16]; unpack8(pp[0], pn); unpack8(pp[1], pn + 8);
    float z = robn[0];
    float n2[16];
#pragma unroll
    for (int j = 0; j < 16; ++j) {
        float x = pn[j] + gpn[g * 16 + j] + hbn[j];
#pragma unroll
        for (int k = 0; k < 8; ++k) x = fmaf(mk[k], wNI[j * 8 + k], x);
        n2[j] = fmaxf(0.f, x);
        z = fmaf(n2[j], rW[j], z);
    }
    outn[v] = sigmoidf_(z);
#pragma unroll
    for (int j = 0; j < 16; ++j) {
        const float s = wsum(n2[j]);
        if (lane == 0) atomicAdd(&nsum[g * 16 + j], s);
    }
}

// K5: hidden global layer + global readout.
__global__ void k_glob_hid(
    const float* __restrict__ esum2, const float* __restrict__ nsum2, const float* __restrict__ g1,
    const float* __restrict__ hWge, const float* __restrict__ hWgn,
    const float* __restrict__ hWgg, const float* __restrict__ hbg,
    const float* __restrict__ roWg, const float* __restrict__ robg,
    float* __restrict__ outg)
{
    const int g = threadIdx.x;
    if (g >= NG) return;
    float gv[4];
#pragma unroll
    for (int o = 0; o < 4; ++o) {
        float x = hbg[o];
#pragma unroll
        for (int k = 0; k < 8; ++k)  x = fmaf(esum2[g * 8 + k] * (1.f / EPG), hWge[o * 8 + k], x);
#pragma unroll
        for (int k = 0; k < 16; ++k) x = fmaf(nsum2[g * 16 + k] * (1.f / NPG), hWgn[o * 16 + k], x);
#pragma unroll
        for (int k = 0; k < 4; ++k)  x = fmaf(g1[g * 4 + k], hWgg[o * 4 + k], x);
        gv[o] = fmaxf(0.f, x);
    }
    float z = robg[0];
#pragma unroll
    for (int o = 0; o < 4; ++o) z = fmaf(gv[o], roWg[o], z);
    outg[g] = sigmoidf_(z);
}

extern "C" void kernel_launch(void* const* d_in, const int* in_sizes, int n_in,
                              void* d_out, int out_size, void* d_ws, size_t ws_size,
                              hipStream_t stream)
{
    const float* nf   = (const float*)d_in[0];
    const float* ef   = (const float*)d_in[1];
    const int*   snd  = (const int*)d_in[2];
    const int*   rcv  = (const int*)d_in[3];
    const float* eWee = (const float*)d_in[6];
    const float* eWes = (const float*)d_in[7];
    const float* ebe  = (const float*)d_in[8];
    const float* eWnn = (const float*)d_in[9];
    const float* eWni = (const float*)d_in[10];
    const float* ebn  = (const float*)d_in[11];
    const float* eWge = (const float*)d_in[12];
    const float* eWgn = (const float*)d_in[13];
    const float* ebg  = (const float*)d_in[14];
    const float* hWee = (const float*)d_in[15];
    const float* hWes = (const float*)d_in[16];
    const float* hWeg = (const float*)d_in[17];
    const float* hbe  = (const float*)d_in[18];
    const float* hWnn = (const float*)d_in[19];
    const float* hWni = (const float*)d_in[20];
    const float* hWng = (const float*)d_in[21];
    const float* hbn  = (const float*)d_in[22];
    const float* hWge = (const float*)d_in[23];
    const float* hWgn = (const float*)d_in[24];
    const float* hWgg = (const float*)d_in[25];
    const float* hbg  = (const float*)d_in[26];
    const float* roWn = (const float*)d_in[27];
    const float* robn = (const float*)d_in[28];
    const float* roWg = (const float*)d_in[29];
    const float* robg = (const float*)d_in[30];

    float*  ws     = (float*)d_ws;
    u32*    edat   = (u32*)(ws + OFF_EDAT);
    __half* sproj  = (__half*)(ws + OFF_SPROJ);
    __half* pnn    = (__half*)(ws + OFF_PNN);
    __half* sprojA = (__half*)(ws + OFF_SPROJA);
    int*    deg    = (int*)(ws + OFF_DEG);
    int*    start  = (int*)(ws + OFF_START);
    int*    h4c    = (int*)(ws + OFF_H4C);
    float*  gs     = ws + OFF_GS;
    float* esum1 = gs + GS_ESUM1;
    float* nsum1 = gs + GS_NSUM1;
    float* esum2 = gs + GS_ESUM2;
    float* nsum2 = gs + GS_NSUM2;
    float* g1    = gs + GS_G1;
    float* gpe   = gs + GS_GPE;
    float* gpn   = gs + GS_GPN;
    float* out   = (float*)d_out;

    k_hist4<<<NG * 4, 512, 0, stream>>>(rcv, h4c);
    k_scan<<<NG, 320, 0, stream>>>(h4c, deg, start);
    k_scatter4<<<NG * 4, 512, 0, stream>>>(ef, snd, rcv, h4c, edat);
    k_node_pre<<<NN / 256, 256, 0, stream>>>(nf, eWes, eWnn, ebe, ebn, sproj, pnn, sprojA, gs);
    k_enc4<<<NN / 256, 256, 0, stream>>>(deg, start, edat, sprojA, sproj, pnn,
                                         eWee, eWni, hWes, hWnn, esum1, nsum1);
    k_glob_enc<<<1, 64, 0, stream>>>(esum1, nsum1, eWge, eWgn, ebg, hWeg, hWng, g1, gpe, gpn);
    k_hid4<<<NN / 256, 256, 0, stream>>>(deg, start, edat, sproj, pnn,
                                         eWee, hWee, hbe, gpe, hWni, hbn, gpn,
                                         roWn, robn, esum2, nsum2, out);
    k_glob_hid<<<1, 64, 0, stream>>>(esum2, nsum2, g1, hWge, hWgn, hWgg, hbg, roWg, robg, out + NN);
}